// Round 5
// baseline (226.726 us; speedup 1.0000x reference)
//
#include <hip/hip_runtime.h>

// Problem shape (fixed by setup_inputs): B=4, N=16384, M=4096, C=64, K=32
static constexpr int Bn = 4;
static constexpr int Nn = 16384;
static constexpr int Mn = 4096;
static constexpr int Cn = 64;
static constexpr int Kn = 32;

static constexpr int CHUNK   = 2048;
static constexpr int WPB     = 8;
static constexpr int THREADS = WPB * 64;    // 512
static constexpr int NCHUNK  = Nn / CHUNK;  // 8
static constexpr int NGROUP  = CHUNK / 256; // 8

// Surrogate-filter margin (dist^2 scale). Worst-case rounding divergence
// between surrogate (yy-2s) and reference dist is ~3e-5; 4e-3 = huge margin,
// admits only ~3 extra exact candidates per query.
static constexpr float EPS = 4e-3f;

typedef unsigned long long ull;

__device__ __forceinline__ ull bcast64(ull v, int srclane) {
  unsigned lo = (unsigned)__builtin_amdgcn_readlane((int)(unsigned)v, srclane);
  unsigned hi = (unsigned)__builtin_amdgcn_readlane((int)(v >> 32), srclane);
  return ((ull)hi << 32) | lo;
}

// # of set bits of m below this lane (v_mbcnt pair)
__device__ __forceinline__ int lanes_below(ull m) {
  return (int)__builtin_amdgcn_mbcnt_hi((unsigned)(m >> 32),
            __builtin_amdgcn_mbcnt_lo((unsigned)m, 0u));
}

// push 64-bit value to lane `dstlane` (full-exec ds_permute pair)
__device__ __forceinline__ ull permute_push64(int dstlane, ull v) {
  const int idx = dstlane << 2;
  int lo = __builtin_amdgcn_ds_permute(idx, (int)(unsigned)v);
  int hi = __builtin_amdgcn_ds_permute(idx, (int)(v >> 32));
  return ((ull)(unsigned)hi << 32) | (unsigned)lo;
}

// full-wave bitonic sort, ascending across 64 lanes
__device__ __forceinline__ ull sort64_asc(ull key, int lane) {
#pragma unroll
  for (int k = 2; k <= 64; k <<= 1) {
#pragma unroll
    for (int j = k >> 1; j > 0; j >>= 1) {
      const ull other = __shfl_xor(key, j);
      const bool keep_min = ((lane & j) == 0) == ((lane & k) == 0);
      const bool take = keep_min ? (other < key) : (other > key);
      key = take ? other : key;
    }
  }
  return key;
}

// lst: asc in lanes 0..31, lanes>=32 == ~0ull. batch: asc across 64 lanes.
// returns top-32 of union (asc in lanes 0..31; lanes>=32 = ~0ull).
__device__ __forceinline__ ull merge_top32(ull lst, ull batch, int lane) {
  const ull bl = __shfl_xor(batch, 31);       // lane i<32 gets batch[31-i]
  ull L = (bl < lst) ? bl : lst;              // bitonic on lanes 0..31
#pragma unroll
  for (int j = 16; j > 0; j >>= 1) {
    const ull other = __shfl_xor(L, j);
    const bool keep_min = (lane & j) == 0;
    const bool take = keep_min ? (other < L) : (other > L);
    L = take ? other : L;
  }
  return (lane < 32) ? L : ~0ull;
}

__device__ __forceinline__ void set_tauf(ull tau, float yyq, float& tau_f) {
  const unsigned th = (unsigned)(tau >> 32);
  // <32 real entries yet -> pass everything
  tau_f = (th == 0xFFFFFFFFu) ? -__builtin_inff()
                              : (yyq - __uint_as_float(th) - EPS) * 0.5f;
}

__device__ __forceinline__ void flush_pend(ull& pend, int& pcnt, ull& lst,
                                           ull& tau, float& tau_f,
                                           float yyq, int lane) {
  const ull key = sort64_asc(pend, lane);   // lanes >= pcnt hold ~0ull
  lst = merge_top32(lst, key, lane);
  tau = bcast64(lst, 31);
  set_tauf(tau, yyq, tau_f);
  pend = ~0ull;
  pcnt = 0;
}

// ---------------- kernel 0: F [B,C,N] -> FT [B,N,C] ----------------
__global__ __launch_bounds__(256) void transpose_f(
    const float* __restrict__ F, float* __restrict__ FT) {
  __shared__ float t[64][65];
  const int tid = threadIdx.x;
  const int bid = blockIdx.x;                 // 256 blocks
  const int xcd = bid & 7;
  const int b   = xcd >> 1;                   // 2 XCDs per batch
  const int nt  = (bid >> 3) * 2 + (xcd & 1); // 0..63
  const float* Fb = F + (size_t)b * Cn * Nn;
  float* FTb = FT + (size_t)b * Nn * Cn;
  for (int sub = 0; sub < 4; ++sub) {
    const int nbase = nt * 256 + sub * 64;
#pragma unroll
    for (int i = 0; i < 16; ++i) {
      const int c = (tid >> 6) + 4 * i;
      t[c][tid & 63] = Fb[(size_t)c * Nn + nbase + (tid & 63)];
    }
    __syncthreads();
#pragma unroll
    for (int i = 0; i < 16; ++i) {
      const int nn = (tid >> 6) + 4 * i;
      FTb[(size_t)(nbase + nn) * Cn + (tid & 63)] = t[tid & 63][nn];
    }
    __syncthreads();
  }
}

// ---------------- kernel 1: kNN + grouped gather ----------------
// Numerics contract (bit-matches jax-GPU expected AND np reference):
//   xx  = (x*x + y*y) + z*z            (reduce, no FMA)  [staged as h=-xx/2]
//   dot = fma(z,qz, fma(y,qy, x*qx))   (GEMM K=3 ascending-k FMA chain)
//   dist= max((xx + yy) - 2*dot, 0)    (separate elementwise ops, no FMA)
// Selection: key = (dist_bits<<32 | idx), exact top-32 == jax.lax.top_k order.
// Fast path: surrogate s = fma(z,qz,fma(y,qy,fma(x,qx,h))); candidate iff
// s >= tau_f where tau_f = (yy - tau_d - EPS)/2. tau only tightens -> filter
// is always a superset of the exact criterion.
__global__ __launch_bounds__(THREADS, 8) void knn_group(
    const float* __restrict__ P,   // [B,3,N]
    const float* __restrict__ Q,   // [B,3,M]
    const float* __restrict__ FT,  // [B,N,C]
    float* __restrict__ out)       // [B,3+C,M,K]
{
#pragma clang fp contract(off)
  __shared__ float lds[4][CHUNK];  // x, y, z, h planes (32 KiB)

  const int tid  = threadIdx.x;
  const int lane = tid & 63;
  const int wid  = tid >> 6;
  const int bid  = blockIdx.x;          // 2048
  const int xcd  = bid & 7;
  const int b    = xcd >> 1;            // 2 XCDs per batch -> L2 locality
  const int tile = (bid >> 3) * 2 + (xcd & 1);  // 0..511
  const int m    = tile * WPB + wid;

  const float* Pb = P + (size_t)b * 3 * Nn;
  const float* Qb = Q + (size_t)b * 3 * Mn;

  const float qx = Qb[m];
  const float qy = Qb[Mn + m];
  const float qz = Qb[2 * Mn + m];
  const float yyq = (qx * qx + qy * qy) + qz * qz;

  const int t4 = tid * 4;

  // ---- stage chunk 0 ----
  {
    float4 vx = *(const float4*)(Pb + t4);
    float4 vy = *(const float4*)(Pb + Nn + t4);
    float4 vz = *(const float4*)(Pb + 2 * Nn + t4);
    float4 vh;
    vh.x = -0.5f * ((vx.x * vx.x + vy.x * vy.x) + vz.x * vz.x);
    vh.y = -0.5f * ((vx.y * vx.y + vy.y * vy.y) + vz.y * vz.y);
    vh.z = -0.5f * ((vx.z * vx.z + vy.z * vy.z) + vz.z * vz.z);
    vh.w = -0.5f * ((vx.w * vx.w + vy.w * vy.w) + vz.w * vz.w);
    *(float4*)&lds[0][t4] = vx;
    *(float4*)&lds[1][t4] = vy;
    *(float4*)&lds[2][t4] = vz;
    *(float4*)&lds[3][t4] = vh;
  }
  __syncthreads();

  // selection state
  ull lst  = ~0ull;                 // sorted-32 in lanes 0..31; >=32: MAX
  ull tau  = ~0ull;
  ull pend = ~0ull;                 // pending candidate buffer (slots 0..62)
  int pcnt = 0;
  float tau_f;
  set_tauf(tau, yyq, tau_f);        // -inf: everything passes initially

  // ---- main scan ----
  for (int ch = 0; ch < NCHUNK; ++ch) {
    const int n0 = ch * CHUNK;

    float4 nx, ny, nz;
    if (ch + 1 < NCHUNK) {
      nx = *(const float4*)(Pb + (n0 + CHUNK) + t4);
      ny = *(const float4*)(Pb + Nn + (n0 + CHUNK) + t4);
      nz = *(const float4*)(Pb + 2 * Nn + (n0 + CHUNK) + t4);
    }

#pragma unroll
    for (int g = 0; g < NGROUP; ++g) {
      const int p = g * 256 + lane * 4;
      const float4 rx = *(const float4*)&lds[0][p];
      const float4 ry = *(const float4*)&lds[1][p];
      const float4 rz = *(const float4*)&lds[2][p];
      const float4 rh = *(const float4*)&lds[3][p];

      // surrogate: s = dot - xx/2 (3 fma/pt)
      const float s0 = fmaf(rz.x, qz, fmaf(ry.x, qy, fmaf(rx.x, qx, rh.x)));
      const float s1 = fmaf(rz.y, qz, fmaf(ry.y, qy, fmaf(rx.y, qx, rh.y)));
      const float s2 = fmaf(rz.z, qz, fmaf(ry.z, qy, fmaf(rx.z, qx, rh.z)));
      const float s3 = fmaf(rz.w, qz, fmaf(ry.w, qy, fmaf(rx.w, qx, rh.w)));

      const float smax = fmaxf(fmaxf(s0, s1), fmaxf(s2, s3));
      if (__any(smax >= tau_f)) {
        const unsigned nb = (unsigned)(n0 + p);
#define SUBW(SX, CX, CY, CZ, CH_, NOFF)                                       \
        {                                                                     \
          ull mj = __ballot((SX) >= tau_f);                                   \
          if (mj) {                                                           \
            const float xxv = -2.0f * (CH_);                                  \
            const float ddv = fmaf((CZ), qz, fmaf((CY), qy, (CX) * qx));      \
            const float dv  = fmaxf((xxv + yyq) - 2.0f * ddv, 0.0f);          \
            const ull kj = ((ull)__float_as_uint(dv) << 32) | (unsigned)(NOFF);\
            int c = (int)__popcll(mj);                                        \
            if (pcnt + c > 63) {                                              \
              flush_pend(pend, pcnt, lst, tau, tau_f, yyq, lane);             \
              mj = __ballot((SX) >= tau_f);                                   \
              c  = (int)__popcll(mj);                                         \
            }                                                                 \
            if (c > 63) {            /* all 64 pass (pre-first-flush) */      \
              const ull key = sort64_asc(kj, lane);                           \
              lst = merge_top32(lst, key, lane);                              \
              tau = bcast64(lst, 31);                                         \
              set_tauf(tau, yyq, tau_f);                                      \
            } else if (c) {                                                   \
              const int prefix = lanes_below(mj);                             \
              const bool pass = (mj >> lane) & 1ull;                          \
              const int dst = pass ? (pcnt + prefix) : 63;                    \
              const ull got = permute_push64(dst, kj);                        \
              const bool take = (lane >= pcnt) && (lane < pcnt + c);          \
              pend = take ? got : pend;                                       \
              pcnt += c;                                                      \
            }                                                                 \
          }                                                                   \
        }
        SUBW(s0, rx.x, ry.x, rz.x, rh.x, nb + 0u)
        SUBW(s1, rx.y, ry.y, rz.y, rh.y, nb + 1u)
        SUBW(s2, rx.z, ry.z, rz.z, rh.z, nb + 2u)
        SUBW(s3, rx.w, ry.w, rz.w, rh.w, nb + 3u)
#undef SUBW
      }
    }
    __syncthreads();

    if (ch + 1 < NCHUNK) {
      float4 vh;
      vh.x = -0.5f * ((nx.x * nx.x + ny.x * ny.x) + nz.x * nz.x);
      vh.y = -0.5f * ((nx.y * nx.y + ny.y * ny.y) + nz.y * nz.y);
      vh.z = -0.5f * ((nx.z * nx.z + ny.z * ny.z) + nz.z * nz.z);
      vh.w = -0.5f * ((nx.w * nx.w + ny.w * ny.w) + nz.w * nz.w);
      *(float4*)&lds[0][t4] = nx;
      *(float4*)&lds[1][t4] = ny;
      *(float4*)&lds[2][t4] = nz;
      *(float4*)&lds[3][t4] = vh;
      __syncthreads();
    }
  }

  // drain remaining candidates
  if (pcnt > 0) flush_pend(pend, pcnt, lst, tau, tau_f, yyq, lane);

  // ---- output: [B, 3+C, M, K] ----
  const size_t MK = (size_t)Mn * Kn;
  float* outb = out + (size_t)b * (3 + Cn) * MK;

  if (lane < 32) {
    const int idx = (int)(__shfl(lst, lane) & 0xffffffffull);
    const float px = Pb[idx];
    const float py = Pb[Nn + idx];
    const float pz = Pb[2 * Nn + idx];
    outb[0 * MK + (size_t)m * Kn + lane] = px - qx;
    outb[1 * MK + (size_t)m * Kn + lane] = py - qy;
    outb[2 * MK + (size_t)m * Kn + lane] = pz - qz;
  }

  // features: coalesced rows from FT, 64B-segment writes
  const float* FTb = FT + (size_t)b * Nn * Cn;
  const int r = lane & 15;
  const int q = lane >> 4;   // 0..3
#pragma unroll
  for (int p2 = 0; p2 < 2; ++p2) {
    const int k = p2 * 16 + r;
    const int idxk = (int)(__shfl(lst, k) & 0xffffffffull);
    const float* row = FTb + (size_t)idxk * Cn;
    float4 v[4];
#pragma unroll
    for (int i = 0; i < 4; ++i)
      v[i] = *(const float4*)(row + (q + 4 * i) * 4);
#pragma unroll
    for (int i = 0; i < 4; ++i) {
      const int c = (q + 4 * i) * 4;
      float* o = outb + (size_t)(3 + c) * MK + (size_t)m * Kn + k;
      o[0 * MK] = v[i].x;
      o[1 * MK] = v[i].y;
      o[2 * MK] = v[i].z;
      o[3 * MK] = v[i].w;
    }
  }
}

extern "C" void kernel_launch(void* const* d_in, const int* in_sizes, int n_in,
                              void* d_out, int out_size, void* d_ws, size_t ws_size,
                              hipStream_t stream) {
  (void)in_sizes; (void)n_in; (void)out_size; (void)ws_size;
  const float* P = (const float*)d_in[0];
  const float* Q = (const float*)d_in[1];
  const float* F = (const float*)d_in[2];
  float* out = (float*)d_out;
  float* FT  = (float*)d_ws;   // 4*16384*64*4 = 16.8 MB

  hipLaunchKernelGGL(transpose_f, dim3(256), dim3(256), 0, stream, F, FT);
  hipLaunchKernelGGL(knn_group, dim3(Bn * Mn / WPB), dim3(THREADS), 0, stream,
                     P, Q, FT, out);
}